// Round 3
// baseline (984.271 us; speedup 1.0000x reference)
//
#include <hip/hip_runtime.h>

#define NTOK 8192
#define DIN  1024
#define DOUT 1024
#define HDIM 4096
#define NEXP 8
#define NPAIR (NTOK * 2)

typedef __attribute__((ext_vector_type(8))) short bf16x8;
typedef __attribute__((ext_vector_type(4))) float f32x4;

__device__ __forceinline__ unsigned short f2bf(float f) {
  union { float f; unsigned u; } v; v.f = f;
  unsigned u = v.u;
  unsigned r = (u + 0x7fffu + ((u >> 16) & 1u)) >> 16;  // RTNE
  return (unsigned short)r;
}

__device__ __forceinline__ void gload16(const void* g, void* l) {
  __builtin_amdgcn_global_load_lds(
      (const __attribute__((address_space(1))) unsigned int*)g,
      (__attribute__((address_space(3))) unsigned int*)l, 16, 0, 0);
}

// ---------------- gate: fp64 dot, scores over 8 hypercube corners, top-2 ----
__global__ void gate_kernel(const float* __restrict__ x, const float* __restrict__ Wg,
                            int* __restrict__ cnt, int* __restrict__ ptok,
                            float* __restrict__ pw) {
  const int lane = threadIdx.x & 63;
  const int t = blockIdx.x * 4 + (threadIdx.x >> 6);
  const float* xr = x + (size_t)t * DIN + lane * 16;
  const float* wr = Wg + (size_t)lane * 16 * 3;
  double d0 = 0, d1 = 0, d2 = 0;
#pragma unroll
  for (int j = 0; j < 16; j++) {
    double xv = xr[j];
    d0 += xv * wr[j * 3 + 0];
    d1 += xv * wr[j * 3 + 1];
    d2 += xv * wr[j * 3 + 2];
  }
#pragma unroll
  for (int o = 32; o > 0; o >>= 1) {
    d0 += __shfl_down(d0, o);
    d1 += __shfl_down(d1, o);
    d2 += __shfl_down(d2, o);
  }
  if (lane == 0) {
    double l0 = d0 > 0 ? d0 : 0, l1 = d1 > 0 ? d1 : 0, l2 = d2 > 0 ? d2 : 0;
    double s[NEXP];
#pragma unroll
    for (int e = 0; e < NEXP; e++)
      s[e] = ((e & 1) ? l0 : -l0) + ((e & 2) ? l1 : -l1) + ((e & 4) ? l2 : -l2);
    int e0 = 0;
    for (int e = 1; e < NEXP; e++) if (s[e] > s[e0]) e0 = e;        // ties -> lowest idx
    int e1 = -1;
    for (int e = 0; e < NEXP; e++) { if (e == e0) continue; if (e1 < 0 || s[e] > s[e1]) e1 = e; }
    double w0 = 1.0 / (1.0 + exp(s[e1] - s[e0]));  // == renormalized softmax pair
    double w1 = 1.0 - w0;
    int p0 = atomicAdd(cnt + e0, 1);
    ptok[e0 * NTOK + p0] = t; pw[e0 * NTOK + p0] = (float)w0;
    int p1 = atomicAdd(cnt + e1, 1);
    ptok[e1 * NTOK + p1] = t; pw[e1 * NTOK + p1] = (float)w1;
  }
}

__global__ void scan_kernel(const int* __restrict__ cnt, int* __restrict__ off) {
  if (threadIdx.x == 0) {
    int a = 0;
    for (int e = 0; e < NEXP; e++) { off[e] = a; a += cnt[e]; }
  }
}

// ---------------- fp32 -> bf16 elementwise --------------------------------
__global__ void cvt_bf16_kernel(const float* __restrict__ src,
                                unsigned short* __restrict__ dst, int n) {
  int i = (blockIdx.x * 256 + threadIdx.x) * 8;
  if (i >= n) return;
  float4 a = *(const float4*)(src + i);
  float4 b = *(const float4*)(src + i + 4);
  __align__(16) unsigned short t[8] = {f2bf(a.x), f2bf(a.y), f2bf(a.z), f2bf(a.w),
                                       f2bf(b.x), f2bf(b.y), f2bf(b.z), f2bf(b.w)};
  *(uint4*)(dst + i) = *(const uint4*)t;
}

// ---------------- fp32 [e][K][N] -> bf16 [e][N][K] transpose ---------------
__global__ void transpose_cvt(const float* __restrict__ src,
                              unsigned short* __restrict__ dst, int K, int N) {
  __shared__ float tile[64][65];
  const size_t base = (size_t)blockIdx.z * K * N;
  const float* s = src + base;
  unsigned short* d = dst + base;
  int n0 = blockIdx.x * 64, k0 = blockIdx.y * 64;
  for (int idx = threadIdx.x; idx < 64 * 16; idx += 256) {
    int r = idx >> 4, c4 = (idx & 15) * 4;
    float4 v = *(const float4*)(s + (size_t)(k0 + r) * N + n0 + c4);
    tile[r][c4 + 0] = v.x; tile[r][c4 + 1] = v.y;
    tile[r][c4 + 2] = v.z; tile[r][c4 + 3] = v.w;
  }
  __syncthreads();
  for (int idx = threadIdx.x; idx < 64 * 8; idx += 256) {
    int nl = idx >> 3, c8 = (idx & 7) * 8;
    __align__(16) unsigned short tmp[8];
#pragma unroll
    for (int j = 0; j < 8; j++) tmp[j] = f2bf(tile[c8 + j][nl]);
    *(uint4*)(d + (size_t)(n0 + nl) * K + k0 + c8) = *(const uint4*)tmp;
  }
}

// ---------------- grouped GEMM1: h = relu(x @ W1[e] + b1[e]) ---------------
// 256x256 tile, BK=32, 1024 threads (4x4 waves), double-buffered 2-phase,
// expert<->XCD co-location (bid&7 == e so one expert's panels live in one L2).
__global__ __launch_bounds__(1024, 2) void gemm1_kernel(
    const unsigned short* __restrict__ xbf,   // [NTOK][DIN]
    const unsigned short* __restrict__ w1t,   // [E][HDIM][DIN]
    const float* __restrict__ b1,             // [E][HDIM]
    const int* __restrict__ cnt, const int* __restrict__ off,
    const int* __restrict__ ptok,
    unsigned short* __restrict__ h)           // [NPAIR][HDIM]
{
  const int bid = blockIdx.x;
  const int e = bid & 7;              // XCD i%8 gets expert i
  const int ce = cnt[e];
  const int idx = bid >> 3;           // 0..511
  const int mt = idx >> 4;            // 0..31
  const int nt = idx & 15;            // 0..15
  const int m0 = mt * 256;
  if (m0 >= ce) return;
  const int n0 = nt * 256;
  const int oe = off[e];
  __shared__ __align__(16) unsigned short lA[2][256 * 32];
  __shared__ __align__(16) unsigned short lB[2][256 * 32];
  const int tid = threadIdx.x;        // 0..1023
  const int lane = tid & 63;
  const int wv = tid >> 6;            // 0..15
  const int wr = wv >> 2, wc = wv & 3;

  const int ra = tid >> 2;            // 0..255 staged row
  const int ka = (tid & 3) * 8;       // k element offset
  const int ta = ptok[e * NTOK + min(m0 + ra, ce - 1)];
  const unsigned short* ga = xbf + (size_t)ta * DIN + ka;
  const unsigned short* wb = w1t + (size_t)e * HDIM * DIN;
  const unsigned short* gb = wb + (size_t)(n0 + ra) * DIN + ka;

  f32x4 acc[4][4] = {};
  const int fr = lane & 15;
  const int fk = (lane >> 4) * 8;

#define STAGE1(buf, kk)                          \
  do {                                           \
    gload16(ga + (kk), &lA[buf][tid * 8]);       \
    gload16(gb + (kk), &lB[buf][tid * 8]);       \
  } while (0)

#define COMPUTE1(buf)                                                        \
  do {                                                                       \
    bf16x8 a[4], b[4];                                                       \
    _Pragma("unroll") for (int i = 0; i < 4; i++)                            \
      a[i] = *(const bf16x8*)(&lA[buf][(wr * 64 + i * 16 + fr) * 32 + fk]);  \
    _Pragma("unroll") for (int i = 0; i < 4; i++)                            \
      b[i] = *(const bf16x8*)(&lB[buf][(wc * 64 + i * 16 + fr) * 32 + fk]);  \
    _Pragma("unroll") for (int mi = 0; mi < 4; mi++)                         \
      _Pragma("unroll") for (int ni = 0; ni < 4; ni++)                       \
        acc[mi][ni] = __builtin_amdgcn_mfma_f32_16x16x32_bf16(               \
            a[mi], b[ni], acc[mi][ni], 0, 0, 0);                             \
  } while (0)

  STAGE1(0, 0);
  asm volatile("s_waitcnt vmcnt(0)" ::: "memory");
  __syncthreads();
  int cur = 0;
  for (int k0 = 32; k0 < DIN; k0 += 32) {
    STAGE1(cur ^ 1, k0);
    COMPUTE1(cur);
    asm volatile("s_waitcnt vmcnt(0)" ::: "memory");
    __syncthreads();
    cur ^= 1;
  }
  COMPUTE1(cur);

  const int cr = (lane >> 4) * 4;
  const int cc = lane & 15;
#pragma unroll
  for (int mi = 0; mi < 4; mi++) {
    int rbase = wr * 64 + mi * 16 + cr;
#pragma unroll
    for (int r = 0; r < 4; r++) {
      int grow = m0 + rbase + r;
      if (grow >= ce) continue;
      size_t hoff = (size_t)(oe + grow) * HDIM;
#pragma unroll
      for (int ni = 0; ni < 4; ni++) {
        int col = n0 + wc * 64 + ni * 16 + cc;
        float v = acc[mi][ni][r] + b1[e * HDIM + col];
        h[hoff + col] = f2bf(v > 0.f ? v : 0.f);
      }
    }
  }
}

// ---------------- grouped GEMM2: out += w * (h @ W2[e] + b2[e]) ------------
__global__ __launch_bounds__(1024, 2) void gemm2_kernel(
    const unsigned short* __restrict__ h,     // [NPAIR][HDIM]
    const unsigned short* __restrict__ w2t,   // [E][DOUT][HDIM]
    const float* __restrict__ b2,             // [E][DOUT]
    const int* __restrict__ cnt, const int* __restrict__ off,
    const int* __restrict__ ptok, const float* __restrict__ pw,
    float* __restrict__ out)                  // [NTOK][DOUT]
{
  const int bid = blockIdx.x;
  const int e = bid & 7;
  const int ce = cnt[e];
  const int idx = bid >> 3;           // 0..127
  const int mt = idx >> 2;            // 0..31
  const int nt = idx & 3;             // 0..3
  const int m0 = mt * 256;
  if (m0 >= ce) return;
  const int n0 = nt * 256;
  const int oe = off[e];
  __shared__ __align__(16) unsigned short lA[2][256 * 32];
  __shared__ __align__(16) unsigned short lB[2][256 * 32];
  const int tid = threadIdx.x;
  const int lane = tid & 63;
  const int wv = tid >> 6;
  const int wr = wv >> 2, wc = wv & 3;

  const int ra = tid >> 2;
  const int ka = (tid & 3) * 8;
  const int rc = min(m0 + ra, ce - 1);
  const unsigned short* ga = h + (size_t)(oe + rc) * HDIM + ka;
  const unsigned short* wbp = w2t + (size_t)e * DOUT * HDIM;
  const unsigned short* gb = wbp + (size_t)(n0 + ra) * HDIM + ka;

  f32x4 acc[4][4] = {};
  const int fr = lane & 15;
  const int fk = (lane >> 4) * 8;

#define STAGE2(buf, kk)                          \
  do {                                           \
    gload16(ga + (kk), &lA[buf][tid * 8]);       \
    gload16(gb + (kk), &lB[buf][tid * 8]);       \
  } while (0)

#define COMPUTE2(buf)                                                        \
  do {                                                                       \
    bf16x8 a[4], b[4];                                                       \
    _Pragma("unroll") for (int i = 0; i < 4; i++)                            \
      a[i] = *(const bf16x8*)(&lA[buf][(wr * 64 + i * 16 + fr) * 32 + fk]);  \
    _Pragma("unroll") for (int i = 0; i < 4; i++)                            \
      b[i] = *(const bf16x8*)(&lB[buf][(wc * 64 + i * 16 + fr) * 32 + fk]);  \
    _Pragma("unroll") for (int mi = 0; mi < 4; mi++)                         \
      _Pragma("unroll") for (int ni = 0; ni < 4; ni++)                       \
        acc[mi][ni] = __builtin_amdgcn_mfma_f32_16x16x32_bf16(               \
            a[mi], b[ni], acc[mi][ni], 0, 0, 0);                             \
  } while (0)

  STAGE2(0, 0);
  asm volatile("s_waitcnt vmcnt(0)" ::: "memory");
  __syncthreads();
  int cur = 0;
  for (int k0 = 32; k0 < HDIM; k0 += 32) {
    STAGE2(cur ^ 1, k0);
    COMPUTE2(cur);
    asm volatile("s_waitcnt vmcnt(0)" ::: "memory");
    __syncthreads();
    cur ^= 1;
  }
  COMPUTE2(cur);

  const int cr = (lane >> 4) * 4;
  const int cc = lane & 15;
#pragma unroll
  for (int mi = 0; mi < 4; mi++) {
    int rbase = wr * 64 + mi * 16 + cr;
#pragma unroll
    for (int r = 0; r < 4; r++) {
      int grow = m0 + rbase + r;
      if (grow >= ce) continue;
      int pidx = e * NTOK + grow;
      int token = ptok[pidx];
      float w = pw[pidx];
#pragma unroll
      for (int ni = 0; ni < 4; ni++) {
        int col = n0 + wc * 64 + ni * 16 + cc;
        float v = (acc[mi][ni][r] + b2[e * DOUT + col]) * w;
        atomicAdd(out + (size_t)token * DOUT + col, v);
      }
    }
  }
}

extern "C" void kernel_launch(void* const* d_in, const int* in_sizes, int n_in,
                              void* d_out, int out_size, void* d_ws, size_t ws_size,
                              hipStream_t stream) {
  const float* x  = (const float*)d_in[0];
  const float* Wg = (const float*)d_in[1];
  const float* W1 = (const float*)d_in[2];
  const float* b1 = (const float*)d_in[3];
  const float* W2 = (const float*)d_in[4];
  const float* b2 = (const float*)d_in[5];
  float* out = (float*)d_out;

  char* ws = (char*)d_ws;
  size_t o = 0;
  auto nxt = [&](size_t b) { char* p = ws + o; o = (o + b + 255) & ~(size_t)255; return p; };
  int* cnt = (int*)nxt(64);
  int* off = (int*)nxt(64);
  int* ptok = (int*)nxt((size_t)NEXP * NTOK * 4);
  float* pw = (float*)nxt((size_t)NEXP * NTOK * 4);
  unsigned short* xbf = (unsigned short*)nxt((size_t)NTOK * DIN * 2);
  unsigned short* w1t = (unsigned short*)nxt((size_t)NEXP * HDIM * DIN * 2);
  unsigned short* w2t = (unsigned short*)nxt((size_t)NEXP * DOUT * HDIM * 2);
  unsigned short* hbuf = (unsigned short*)nxt((size_t)NPAIR * HDIM * 2);

  hipMemsetAsync(cnt, 0, 64, stream);
  hipMemsetAsync(out, 0, (size_t)NTOK * DOUT * 4, stream);

  gate_kernel<<<NTOK / 4, 256, 0, stream>>>(x, Wg, cnt, ptok, pw);
  scan_kernel<<<1, 64, 0, stream>>>(cnt, off);
  cvt_bf16_kernel<<<(NTOK * DIN / 8) / 256, 256, 0, stream>>>(x, xbf, NTOK * DIN);
  transpose_cvt<<<dim3(HDIM / 64, DIN / 64, NEXP), 256, 0, stream>>>(W1, w1t, DIN, HDIM);
  transpose_cvt<<<dim3(DOUT / 64, HDIM / 64, NEXP), 256, 0, stream>>>(W2, w2t, HDIM, DOUT);

  // 1-D grids: bid&7 = expert (XCD-colocated), rest = (mt,nt) tiles.
  gemm1_kernel<<<8 * (NTOK / 256) * (HDIM / 256), 1024, 0, stream>>>(
      xbf, w1t, b1, cnt, off, ptok, hbuf);
  gemm2_kernel<<<8 * (NTOK / 256) * (DOUT / 256), 1024, 0, stream>>>(
      hbuf, w2t, b2, cnt, off, ptok, pw, out);
}

// Round 4
// 901.257 us; speedup vs baseline: 1.0921x; 1.0921x over previous
//
#include <hip/hip_runtime.h>

#define NTOK 8192
#define DIN  1024
#define DOUT 1024
#define HDIM 4096
#define NEXP 8
#define NPAIR (NTOK * 2)

typedef __attribute__((ext_vector_type(8))) short bf16x8;
typedef __attribute__((ext_vector_type(4))) float f32x4;

__device__ __forceinline__ unsigned short f2bf(float f) {
  union { float f; unsigned u; } v; v.f = f;
  unsigned u = v.u;
  unsigned r = (u + 0x7fffu + ((u >> 16) & 1u)) >> 16;  // RTNE
  return (unsigned short)r;
}

__device__ __forceinline__ void gload16(const void* g, void* l) {
  __builtin_amdgcn_global_load_lds(
      (const __attribute__((address_space(1))) unsigned int*)g,
      (__attribute__((address_space(3))) unsigned int*)l, 16, 0, 0);
}

// ---------------- gate: fp64 dot, scores over 8 hypercube corners, top-2 ----
__global__ void gate_kernel(const float* __restrict__ x, const float* __restrict__ Wg,
                            int* __restrict__ cnt, int* __restrict__ ptok,
                            float* __restrict__ pw) {
  const int lane = threadIdx.x & 63;
  const int t = blockIdx.x * 4 + (threadIdx.x >> 6);
  const float* xr = x + (size_t)t * DIN + lane * 16;
  const float* wr = Wg + (size_t)lane * 16 * 3;
  double d0 = 0, d1 = 0, d2 = 0;
#pragma unroll
  for (int j = 0; j < 16; j++) {
    double xv = xr[j];
    d0 += xv * wr[j * 3 + 0];
    d1 += xv * wr[j * 3 + 1];
    d2 += xv * wr[j * 3 + 2];
  }
#pragma unroll
  for (int o = 32; o > 0; o >>= 1) {
    d0 += __shfl_down(d0, o);
    d1 += __shfl_down(d1, o);
    d2 += __shfl_down(d2, o);
  }
  if (lane == 0) {
    double l0 = d0 > 0 ? d0 : 0, l1 = d1 > 0 ? d1 : 0, l2 = d2 > 0 ? d2 : 0;
    double s[NEXP];
#pragma unroll
    for (int e = 0; e < NEXP; e++)
      s[e] = ((e & 1) ? l0 : -l0) + ((e & 2) ? l1 : -l1) + ((e & 4) ? l2 : -l2);
    int e0 = 0;
    for (int e = 1; e < NEXP; e++) if (s[e] > s[e0]) e0 = e;        // ties -> lowest idx
    int e1 = -1;
    for (int e = 0; e < NEXP; e++) { if (e == e0) continue; if (e1 < 0 || s[e] > s[e1]) e1 = e; }
    double w0 = 1.0 / (1.0 + exp(s[e1] - s[e0]));  // == renormalized softmax pair
    double w1 = 1.0 - w0;
    int p0 = atomicAdd(cnt + e0, 1);
    ptok[e0 * NTOK + p0] = t; pw[e0 * NTOK + p0] = (float)w0;
    int p1 = atomicAdd(cnt + e1, 1);
    ptok[e1 * NTOK + p1] = t; pw[e1 * NTOK + p1] = (float)w1;
  }
}

__global__ void scan_kernel(const int* __restrict__ cnt, int* __restrict__ off) {
  if (threadIdx.x == 0) {
    int a = 0;
    for (int e = 0; e < NEXP; e++) { off[e] = a; a += cnt[e]; }
  }
}

// ---------------- fp32 -> bf16 elementwise --------------------------------
__global__ void cvt_bf16_kernel(const float* __restrict__ src,
                                unsigned short* __restrict__ dst, int n) {
  int i = (blockIdx.x * 256 + threadIdx.x) * 8;
  if (i >= n) return;
  float4 a = *(const float4*)(src + i);
  float4 b = *(const float4*)(src + i + 4);
  __align__(16) unsigned short t[8] = {f2bf(a.x), f2bf(a.y), f2bf(a.z), f2bf(a.w),
                                       f2bf(b.x), f2bf(b.y), f2bf(b.z), f2bf(b.w)};
  *(uint4*)(dst + i) = *(const uint4*)t;
}

// ---------------- fp32 [e][K][N] -> bf16 [e][N][K] transpose ---------------
__global__ void transpose_cvt(const float* __restrict__ src,
                              unsigned short* __restrict__ dst, int K, int N) {
  __shared__ float tile[64][65];
  const size_t base = (size_t)blockIdx.z * K * N;
  const float* s = src + base;
  unsigned short* d = dst + base;
  int n0 = blockIdx.x * 64, k0 = blockIdx.y * 64;
  for (int idx = threadIdx.x; idx < 64 * 16; idx += 256) {
    int r = idx >> 4, c4 = (idx & 15) * 4;
    float4 v = *(const float4*)(s + (size_t)(k0 + r) * N + n0 + c4);
    tile[r][c4 + 0] = v.x; tile[r][c4 + 1] = v.y;
    tile[r][c4 + 2] = v.z; tile[r][c4 + 3] = v.w;
  }
  __syncthreads();
  for (int idx = threadIdx.x; idx < 64 * 8; idx += 256) {
    int nl = idx >> 3, c8 = (idx & 7) * 8;
    __align__(16) unsigned short tmp[8];
#pragma unroll
    for (int j = 0; j < 8; j++) tmp[j] = f2bf(tile[c8 + j][nl]);
    *(uint4*)(d + (size_t)(n0 + nl) * K + k0 + c8) = *(const uint4*)tmp;
  }
}

// ==========================================================================
// 256x256x64 8-wave 4-phase grouped GEMM template pieces.
// LDS (dynamic, 128 KB): [buf(2)][ A 256x64 (32KB) | B 256x64 (32KB) ]
// bank-swizzle: logical (row, byte c in [0,128)) stored at c ^ ((row&7)<<4).
// gload_lds writes linearly; global SOURCE is inverse-swizzled (same XOR).
// ==========================================================================

// per-phase macros (shared by both kernels via local bindings)
#define RD_A(qm, bufb)                                                         \
  _Pragma("unroll") for (int fi = 0; fi < 4; fi++)                             \
    _Pragma("unroll") for (int ks = 0; ks < 2; ks++)                           \
      areg[fi][ks] = *(const bf16x8*)(lds + (bufb) +                           \
          (unsigned)((rowA_base + (qm) * 64 + fi * 16) * 128 +                 \
                     ((ks * 64 + hi * 16) ^ cxor)));

#define RD_B(qn, breg, bufb)                                                   \
  _Pragma("unroll") for (int fj = 0; fj < 2; fj++)                             \
    _Pragma("unroll") for (int ks = 0; ks < 2; ks++)                           \
      breg[fj][ks] = *(const bf16x8*)(lds + (bufb) + 32768u +                  \
          (unsigned)((rowB_base + (qn) * 32 + fj * 16) * 128 +                 \
                     ((ks * 64 + hi * 16) ^ cxor)));

#define MM_Q(qm, qn, breg)                                                     \
  _Pragma("unroll") for (int fi = 0; fi < 4; fi++)                             \
    _Pragma("unroll") for (int fj = 0; fj < 2; fj++)                           \
      _Pragma("unroll") for (int ks = 0; ks < 2; ks++)                         \
        acc[(qm) * 4 + fi][(qn) * 2 + fj] =                                    \
            __builtin_amdgcn_mfma_f32_16x16x32_bf16(                           \
                areg[fi][ks], breg[fj][ks], acc[(qm) * 4 + fi][(qn) * 2 + fj], \
                0, 0, 0);

// stage half hh (0,1 = A halves; 2,3 = B halves) of next tile into buf bv
#define STG(hh, bv, kel)                                                       \
  do {                                                                         \
    unsigned db = (unsigned)(bv) * 65536u +                                    \
                  (((hh) < 2) ? (unsigned)(hh) * 16384u                        \
                              : 32768u + (unsigned)((hh) - 2) * 16384u);       \
    const unsigned short* s0 = ((hh) < 2) ? aptr[(hh) * 2] : bptr[((hh) - 2) * 2];         \
    const unsigned short* s1 = ((hh) < 2) ? aptr[(hh) * 2 + 1] : bptr[((hh) - 2) * 2 + 1]; \
    gload16(s0 + (kel), lds + db + (unsigned)tid * 16u);                       \
    gload16(s1 + (kel), lds + db + 8192u + (unsigned)tid * 16u);               \
  } while (0)

#define PH_TOP(hh)                                                             \
  if (more) STG(hh, bufn, kel);

#define PH_MFMA(qm, qn, breg)                                                  \
  __builtin_amdgcn_s_barrier();                                                \
  __builtin_amdgcn_sched_barrier(0);                                           \
  __builtin_amdgcn_s_setprio(1);                                               \
  MM_Q(qm, qn, breg);                                                          \
  __builtin_amdgcn_s_setprio(0);                                               \
  __builtin_amdgcn_sched_barrier(0);

// ---------------- grouped GEMM1: h = relu(x @ W1[e] + b1[e]) ---------------
__global__ __launch_bounds__(512, 1) void gemm1_kernel(
    const unsigned short* __restrict__ xbf,   // [NTOK][DIN]
    const unsigned short* __restrict__ w1t,   // [E][HDIM][DIN]
    const float* __restrict__ b1,             // [E][HDIM]
    const int* __restrict__ cnt, const int* __restrict__ off,
    const int* __restrict__ ptok,
    unsigned short* __restrict__ h)           // [NPAIR][HDIM]
{
  extern __shared__ char lds[];
  const int bid = blockIdx.x;
  const int e = bid & 7;                      // expert <-> XCD colocation
  const int ce = cnt[e];
  const int idx = bid >> 3;
  const int mt = idx >> 4;                    // NT = HDIM/256 = 16
  const int nt = idx & 15;
  const int m0 = mt * 256;
  if (m0 >= ce) return;
  const int n0 = nt * 256;
  const int oe = off[e];
  const int tid = threadIdx.x;
  const int lane = tid & 63;
  const int wid = tid >> 6;
  const int wm = wid >> 2;                    // 0..1
  const int wn = wid & 3;                     // 0..3

  // staging source pointers (inverse-swizzled k offset)
  const int kofs = ((tid & 7) * 8) ^ (((tid >> 3) & 7) << 3);
  const int rth = tid >> 3;                   // 0..63
  const unsigned short* aptr[4];
  const unsigned short* bptr[4];
  const unsigned short* wb = w1t + (size_t)e * HDIM * DIN;
#pragma unroll
  for (int i = 0; i < 4; i++) {
    int r = rth + i * 64;
    int ta = ptok[e * NTOK + min(m0 + r, ce - 1)];
    aptr[i] = xbf + (size_t)ta * DIN + kofs;
    bptr[i] = wb + (size_t)(n0 + r) * DIN + kofs;
  }

  const int fr = lane & 15;
  const int hi = lane >> 4;
  const int cxor = (fr & 7) << 4;
  const int rowA_base = wm * 128 + fr;
  const int rowB_base = wn * 64 + fr;

  f32x4 acc[8][4] = {};
  bf16x8 areg[4][2], b0reg[2][2], b1reg[2][2];

  // prologue: stage tile 0 into buf 0
  {
    const bool more = true; const int bufn = 0; const int kel = 0;
    PH_TOP(0); PH_TOP(1); PH_TOP(2); PH_TOP(3);
  }

  const int KT = DIN / 64;   // 16
  for (int t = 0; t < KT; t++) {
    const unsigned bb = (unsigned)(t & 1) * 65536u;
    const int bufn = (t + 1) & 1;
    const int kel = (t + 1) * 64;
    const bool more = (t + 1 < KT);
    // ---- phase 0: quad (0,0); reads A0,B0,B1 ----
    PH_TOP(0);
    if (more) asm volatile("s_waitcnt vmcnt(2)" ::: "memory");
    else      asm volatile("s_waitcnt vmcnt(0)" ::: "memory");
    __builtin_amdgcn_s_barrier();
    __builtin_amdgcn_sched_barrier(0);
    RD_A(0, bb); RD_B(0, b0reg, bb); RD_B(1, b1reg, bb);
    __builtin_amdgcn_sched_barrier(0);
    __builtin_amdgcn_s_setprio(1);
    MM_Q(0, 0, b0reg);
    __builtin_amdgcn_s_setprio(0);
    __builtin_amdgcn_sched_barrier(0);
    __builtin_amdgcn_s_barrier();
    // ---- phase 1: quad (0,1); then read A1 for next phases ----
    PH_TOP(1);
    PH_MFMA(0, 1, b1reg);
    RD_A(1, bb);
    __builtin_amdgcn_sched_barrier(0);
    __builtin_amdgcn_s_barrier();
    // ---- phase 2: quad (1,1) ----
    PH_TOP(2);
    PH_MFMA(1, 1, b1reg);
    __builtin_amdgcn_s_barrier();
    // ---- phase 3: quad (1,0) ----
    PH_TOP(3);
    PH_MFMA(1, 0, b0reg);
    __builtin_amdgcn_s_barrier();
  }

  // epilogue: bias + relu + bf16 store
#pragma unroll
  for (int am = 0; am < 8; am++) {
    int rbase = wm * 128 + am * 16 + hi * 4;
#pragma unroll
    for (int r = 0; r < 4; r++) {
      int grow = m0 + rbase + r;
      if (grow >= ce) continue;
      size_t hoff = (size_t)(oe + grow) * HDIM;
#pragma unroll
      for (int an = 0; an < 4; an++) {
        int col = n0 + wn * 64 + an * 16 + fr;
        float v = acc[am][an][r] + b1[e * HDIM + col];
        h[hoff + col] = f2bf(v > 0.f ? v : 0.f);
      }
    }
  }
}

// ---------------- grouped GEMM2: out += w * (h @ W2[e] + b2[e]) ------------
__global__ __launch_bounds__(512, 1) void gemm2_kernel(
    const unsigned short* __restrict__ h,     // [NPAIR][HDIM]
    const unsigned short* __restrict__ w2t,   // [E][DOUT][HDIM]
    const float* __restrict__ b2,             // [E][DOUT]
    const int* __restrict__ cnt, const int* __restrict__ off,
    const int* __restrict__ ptok, const float* __restrict__ pw,
    float* __restrict__ out)                  // [NTOK][DOUT]
{
  extern __shared__ char lds[];
  const int bid = blockIdx.x;
  const int e = bid & 7;
  const int ce = cnt[e];
  const int idx = bid >> 3;
  const int mt = idx >> 2;                    // NT = DOUT/256 = 4
  const int nt = idx & 3;
  const int m0 = mt * 256;
  if (m0 >= ce) return;
  const int n0 = nt * 256;
  const int oe = off[e];
  const int tid = threadIdx.x;
  const int lane = tid & 63;
  const int wid = tid >> 6;
  const int wm = wid >> 2;
  const int wn = wid & 3;

  const int kofs = ((tid & 7) * 8) ^ (((tid >> 3) & 7) << 3);
  const int rth = tid >> 3;
  const unsigned short* aptr[4];
  const unsigned short* bptr[4];
  const unsigned short* wb = w2t + (size_t)e * DOUT * HDIM;
#pragma unroll
  for (int i = 0; i < 4; i++) {
    int r = rth + i * 64;
    int rc = min(m0 + r, ce - 1);
    aptr[i] = h + (size_t)(oe + rc) * HDIM + kofs;
    bptr[i] = wb + (size_t)(n0 + r) * HDIM + kofs;
  }

  const int fr = lane & 15;
  const int hi = lane >> 4;
  const int cxor = (fr & 7) << 4;
  const int rowA_base = wm * 128 + fr;
  const int rowB_base = wn * 64 + fr;

  f32x4 acc[8][4] = {};
  bf16x8 areg[4][2], b0reg[2][2], b1reg[2][2];

  {
    const bool more = true; const int bufn = 0; const int kel = 0;
    PH_TOP(0); PH_TOP(1); PH_TOP(2); PH_TOP(3);
  }

  const int KT = HDIM / 64;   // 64
  for (int t = 0; t < KT; t++) {
    const unsigned bb = (unsigned)(t & 1) * 65536u;
    const int bufn = (t + 1) & 1;
    const int kel = (t + 1) * 64;
    const bool more = (t + 1 < KT);
    PH_TOP(0);
    if (more) asm volatile("s_waitcnt vmcnt(2)" ::: "memory");
    else      asm volatile("s_waitcnt vmcnt(0)" ::: "memory");
    __builtin_amdgcn_s_barrier();
    __builtin_amdgcn_sched_barrier(0);
    RD_A(0, bb); RD_B(0, b0reg, bb); RD_B(1, b1reg, bb);
    __builtin_amdgcn_sched_barrier(0);
    __builtin_amdgcn_s_setprio(1);
    MM_Q(0, 0, b0reg);
    __builtin_amdgcn_s_setprio(0);
    __builtin_amdgcn_sched_barrier(0);
    __builtin_amdgcn_s_barrier();
    PH_TOP(1);
    PH_MFMA(0, 1, b1reg);
    RD_A(1, bb);
    __builtin_amdgcn_sched_barrier(0);
    __builtin_amdgcn_s_barrier();
    PH_TOP(2);
    PH_MFMA(1, 1, b1reg);
    __builtin_amdgcn_s_barrier();
    PH_TOP(3);
    PH_MFMA(1, 0, b0reg);
    __builtin_amdgcn_s_barrier();
  }

  // epilogue: weighted atomic accumulate
#pragma unroll
  for (int am = 0; am < 8; am++) {
    int rbase = wm * 128 + am * 16 + hi * 4;
#pragma unroll
    for (int r = 0; r < 4; r++) {
      int grow = m0 + rbase + r;
      if (grow >= ce) continue;
      int pidx = e * NTOK + grow;
      int token = ptok[pidx];
      float w = pw[pidx];
#pragma unroll
      for (int an = 0; an < 4; an++) {
        int col = n0 + wn * 64 + an * 16 + fr;
        float v = (acc[am][an][r] + b2[e * DOUT + col]) * w;
        atomicAdd(out + (size_t)token * DOUT + col, v);
      }
    }
  }
}

extern "C" void kernel_launch(void* const* d_in, const int* in_sizes, int n_in,
                              void* d_out, int out_size, void* d_ws, size_t ws_size,
                              hipStream_t stream) {
  const float* x  = (const float*)d_in[0];
  const float* Wg = (const float*)d_in[1];
  const float* W1 = (const float*)d_in[2];
  const float* b1 = (const float*)d_in[3];
  const float* W2 = (const float*)d_in[4];
  const float* b2 = (const float*)d_in[5];
  float* out = (float*)d_out;

  char* ws = (char*)d_ws;
  size_t o = 0;
  auto nxt = [&](size_t b) { char* p = ws + o; o = (o + b + 255) & ~(size_t)255; return p; };
  int* cnt = (int*)nxt(64);
  int* off = (int*)nxt(64);
  int* ptok = (int*)nxt((size_t)NEXP * NTOK * 4);
  float* pw = (float*)nxt((size_t)NEXP * NTOK * 4);
  unsigned short* xbf = (unsigned short*)nxt((size_t)NTOK * DIN * 2);
  unsigned short* w1t = (unsigned short*)nxt((size_t)NEXP * HDIM * DIN * 2);
  unsigned short* w2t = (unsigned short*)nxt((size_t)NEXP * DOUT * HDIM * 2);
  unsigned short* hbuf = (unsigned short*)nxt((size_t)NPAIR * HDIM * 2);

  hipFuncSetAttribute((const void*)gemm1_kernel,
                      hipFuncAttributeMaxDynamicSharedMemorySize, 131072);
  hipFuncSetAttribute((const void*)gemm2_kernel,
                      hipFuncAttributeMaxDynamicSharedMemorySize, 131072);

  hipMemsetAsync(cnt, 0, 64, stream);
  hipMemsetAsync(out, 0, (size_t)NTOK * DOUT * 4, stream);

  gate_kernel<<<NTOK / 4, 256, 0, stream>>>(x, Wg, cnt, ptok, pw);
  scan_kernel<<<1, 64, 0, stream>>>(cnt, off);
  cvt_bf16_kernel<<<(NTOK * DIN / 8) / 256, 256, 0, stream>>>(x, xbf, NTOK * DIN);
  transpose_cvt<<<dim3(HDIM / 64, DIN / 64, NEXP), 256, 0, stream>>>(W1, w1t, DIN, HDIM);
  transpose_cvt<<<dim3(DOUT / 64, HDIM / 64, NEXP), 256, 0, stream>>>(W2, w2t, HDIM, DOUT);

  gemm1_kernel<<<8 * (NTOK / 256) * (HDIM / 256), 512, 131072, stream>>>(
      xbf, w1t, b1, cnt, off, ptok, hbuf);
  gemm2_kernel<<<8 * (NTOK / 256) * (DOUT / 256), 512, 131072, stream>>>(
      hbuf, w2t, b2, cnt, off, ptok, pw, out);
}

// Round 5
// 887.355 us; speedup vs baseline: 1.1092x; 1.0157x over previous
//
#include <hip/hip_runtime.h>

#define NTOK 8192
#define DIN  1024
#define DOUT 1024
#define HDIM 4096
#define NEXP 8
#define NPAIR (NTOK * 2)

typedef __attribute__((ext_vector_type(8))) short bf16x8;
typedef __attribute__((ext_vector_type(4))) float f32x4;

__device__ __forceinline__ unsigned short f2bf(float f) {
  union { float f; unsigned u; } v; v.f = f;
  unsigned u = v.u;
  unsigned r = (u + 0x7fffu + ((u >> 16) & 1u)) >> 16;  // RTNE
  return (unsigned short)r;
}

__device__ __forceinline__ void gload16(const void* g, void* l) {
  __builtin_amdgcn_global_load_lds(
      (const __attribute__((address_space(1))) unsigned int*)g,
      (__attribute__((address_space(3))) unsigned int*)l, 16, 0, 0);
}

// opaque LDS read: compiler cannot alias-analyze -> no conservative vmcnt drains
__device__ __forceinline__ bf16x8 ds_read128(unsigned addr) {
  bf16x8 r;
  asm volatile("ds_read_b128 %0, %1" : "=&v"(r) : "v"(addr));
  return r;
}

#define LGKM4() asm volatile("s_waitcnt lgkmcnt(4)" ::: "memory")
#define LGKM0() asm volatile("s_waitcnt lgkmcnt(0)" ::: "memory")
#define VM0()   asm volatile("s_waitcnt vmcnt(0)" ::: "memory")
#define SB0()   __builtin_amdgcn_sched_barrier(0)

// ---------------- gate: fp64 dot, scores over 8 hypercube corners, top-2 ----
__global__ void gate_kernel(const float* __restrict__ x, const float* __restrict__ Wg,
                            int* __restrict__ cnt, int* __restrict__ ptok,
                            float* __restrict__ pw) {
  const int lane = threadIdx.x & 63;
  const int t = blockIdx.x * 4 + (threadIdx.x >> 6);
  const float* xr = x + (size_t)t * DIN + lane * 16;
  const float* wr = Wg + (size_t)lane * 16 * 3;
  double d0 = 0, d1 = 0, d2 = 0;
#pragma unroll
  for (int j = 0; j < 16; j++) {
    double xv = xr[j];
    d0 += xv * wr[j * 3 + 0];
    d1 += xv * wr[j * 3 + 1];
    d2 += xv * wr[j * 3 + 2];
  }
#pragma unroll
  for (int o = 32; o > 0; o >>= 1) {
    d0 += __shfl_down(d0, o);
    d1 += __shfl_down(d1, o);
    d2 += __shfl_down(d2, o);
  }
  if (lane == 0) {
    double l0 = d0 > 0 ? d0 : 0, l1 = d1 > 0 ? d1 : 0, l2 = d2 > 0 ? d2 : 0;
    double s[NEXP];
#pragma unroll
    for (int e = 0; e < NEXP; e++)
      s[e] = ((e & 1) ? l0 : -l0) + ((e & 2) ? l1 : -l1) + ((e & 4) ? l2 : -l2);
    int e0 = 0;
    for (int e = 1; e < NEXP; e++) if (s[e] > s[e0]) e0 = e;        // ties -> lowest idx
    int e1 = -1;
    for (int e = 0; e < NEXP; e++) { if (e == e0) continue; if (e1 < 0 || s[e] > s[e1]) e1 = e; }
    double w0 = 1.0 / (1.0 + exp(s[e1] - s[e0]));  // == renormalized softmax pair
    double w1 = 1.0 - w0;
    int p0 = atomicAdd(cnt + e0, 1);
    ptok[e0 * NTOK + p0] = t; pw[e0 * NTOK + p0] = (float)w0;
    int p1 = atomicAdd(cnt + e1, 1);
    ptok[e1 * NTOK + p1] = t; pw[e1 * NTOK + p1] = (float)w1;
  }
}

__global__ void scan_kernel(const int* __restrict__ cnt, int* __restrict__ off) {
  if (threadIdx.x == 0) {
    int a = 0;
    for (int e = 0; e < NEXP; e++) { off[e] = a; a += cnt[e]; }
  }
}

// ---------------- fp32 -> bf16 elementwise --------------------------------
__global__ void cvt_bf16_kernel(const float* __restrict__ src,
                                unsigned short* __restrict__ dst, int n) {
  int i = (blockIdx.x * 256 + threadIdx.x) * 8;
  if (i >= n) return;
  float4 a = *(const float4*)(src + i);
  float4 b = *(const float4*)(src + i + 4);
  __align__(16) unsigned short t[8] = {f2bf(a.x), f2bf(a.y), f2bf(a.z), f2bf(a.w),
                                       f2bf(b.x), f2bf(b.y), f2bf(b.z), f2bf(b.w)};
  *(uint4*)(dst + i) = *(const uint4*)t;
}

// ---------------- fp32 [e][K][N] -> bf16 [e][N][K] transpose ---------------
__global__ void transpose_cvt(const float* __restrict__ src,
                              unsigned short* __restrict__ dst, int K, int N) {
  __shared__ float tile[64][65];
  const size_t base = (size_t)blockIdx.z * K * N;
  const float* s = src + base;
  unsigned short* d = dst + base;
  int n0 = blockIdx.x * 64, k0 = blockIdx.y * 64;
  for (int idx = threadIdx.x; idx < 64 * 16; idx += 256) {
    int r = idx >> 4, c4 = (idx & 15) * 4;
    float4 v = *(const float4*)(s + (size_t)(k0 + r) * N + n0 + c4);
    tile[r][c4 + 0] = v.x; tile[r][c4 + 1] = v.y;
    tile[r][c4 + 2] = v.z; tile[r][c4 + 3] = v.w;
  }
  __syncthreads();
  for (int idx = threadIdx.x; idx < 64 * 8; idx += 256) {
    int nl = idx >> 3, c8 = (idx & 7) * 8;
    __align__(16) unsigned short tmp[8];
#pragma unroll
    for (int j = 0; j < 8; j++) tmp[j] = f2bf(tile[c8 + j][nl]);
    *(uint4*)(d + (size_t)(n0 + nl) * K + k0 + c8) = *(const uint4*)tmp;
  }
}

// ==========================================================================
// 256x256x64 8-wave grouped GEMM, 1 barrier + 1 vmcnt(0) per K-tile.
// LDS (dynamic, 128 KB): [buf(2)][ A 256x64 (32KB) | B 256x64 (32KB) ]
// swizzle: logical (row, byte c in [0,128)) stored at c ^ ((row&7)<<4);
// gload_lds dest linear, global SOURCE inverse-swizzled (verified r4).
// All LDS reads are opaque inline-asm ds_read_b128 with counted lgkmcnt.
// ==========================================================================

#define STG(hh, bv, kel)                                                       \
  do {                                                                         \
    unsigned db = (unsigned)(bv) * 65536u +                                    \
                  (((hh) < 2) ? (unsigned)(hh) * 16384u                        \
                              : 32768u + (unsigned)((hh) - 2) * 16384u);       \
    const unsigned short* s0 = ((hh) < 2) ? aptr[(hh) * 2] : bptr[((hh) - 2) * 2];         \
    const unsigned short* s1 = ((hh) < 2) ? aptr[(hh) * 2 + 1] : bptr[((hh) - 2) * 2 + 1]; \
    gload16(s0 + (kel), lds + db + (unsigned)tid * 16u);                       \
    gload16(s1 + (kel), lds + db + 8192u + (unsigned)tid * 16u);               \
  } while (0)

#define RD_A(qm, bb)                                                           \
  _Pragma("unroll") for (int fi = 0; fi < 4; fi++) {                           \
    areg[fi][0] = ds_read128(aoff + (bb) + (qm) * 8192u + fi * 2048u + kx0);   \
    areg[fi][1] = ds_read128(aoff + (bb) + (qm) * 8192u + fi * 2048u + kx1);   \
  }

#define RD_B(qn, breg, bb)                                                     \
  _Pragma("unroll") for (int fj = 0; fj < 2; fj++) {                           \
    breg[fj][0] = ds_read128(boff + (bb) + (qn) * 4096u + fj * 2048u + kx0);   \
    breg[fj][1] = ds_read128(boff + (bb) + (qn) * 4096u + fj * 2048u + kx1);   \
  }

#define MM(qm, qn, breg)                                                       \
  __builtin_amdgcn_s_setprio(1);                                               \
  _Pragma("unroll") for (int ks = 0; ks < 2; ks++)                             \
    _Pragma("unroll") for (int fi = 0; fi < 4; fi++)                           \
      _Pragma("unroll") for (int fj = 0; fj < 2; fj++)                         \
        acc[(qm) * 4 + fi][(qn) * 2 + fj] =                                    \
            __builtin_amdgcn_mfma_f32_16x16x32_bf16(                           \
                areg[fi][ks], breg[fj][ks], acc[(qm) * 4 + fi][(qn) * 2 + fj], \
                0, 0, 0);                                                      \
  __builtin_amdgcn_s_setprio(0);

#define KLOOP(KT)                                                              \
  STG(0, 0, 0); STG(1, 0, 0); STG(2, 0, 0); STG(3, 0, 0);                      \
  VM0();                                                                       \
  __builtin_amdgcn_s_barrier();                                                \
  for (int t = 0; t < (KT); t++) {                                             \
    const unsigned bb = (unsigned)(t & 1) * 65536u;                            \
    const int bufn = (t + 1) & 1;                                              \
    const int kel = (t + 1) * 64;                                              \
    const bool more = (t + 1 < (KT));                                          \
    RD_A(0, bb);                                                               \
    RD_B(0, b0reg, bb);                                                        \
    RD_B(1, b1reg, bb);                                                        \
    if (more) { STG(0, bufn, kel); STG(1, bufn, kel); }                        \
    LGKM4(); SB0();                                                            \
    MM(0, 0, b0reg);                                                           \
    LGKM0(); SB0();                                                            \
    MM(0, 1, b1reg);                                                           \
    RD_A(1, bb);                                                               \
    if (more) { STG(2, bufn, kel); STG(3, bufn, kel); }                        \
    LGKM0(); SB0();                                                            \
    MM(1, 1, b1reg);                                                           \
    MM(1, 0, b0reg);                                                           \
    VM0();                                                                     \
    __builtin_amdgcn_s_barrier();                                              \
  }

// ---------------- grouped GEMM1: h = relu(x @ W1[e] + b1[e]) ---------------
__global__ __launch_bounds__(512, 1) void gemm1_kernel(
    const unsigned short* __restrict__ xbf,   // [NTOK][DIN]
    const unsigned short* __restrict__ w1t,   // [E][HDIM][DIN]
    const float* __restrict__ b1,             // [E][HDIM]
    const int* __restrict__ cnt, const int* __restrict__ off,
    const int* __restrict__ ptok,
    unsigned short* __restrict__ h)           // [NPAIR][HDIM]
{
  extern __shared__ char lds[];
  const int bid = blockIdx.x;
  const int e = bid & 7;                      // expert <-> XCD colocation
  const int ce = cnt[e];
  const int idx = bid >> 3;
  const int mt = idx >> 4;                    // NT = HDIM/256 = 16
  const int nt = idx & 15;
  const int m0 = mt * 256;
  if (m0 >= ce) return;
  const int n0 = nt * 256;
  const int oe = off[e];
  const int tid = threadIdx.x;
  const int lane = tid & 63;
  const int wid = tid >> 6;
  const int wm = wid >> 2;                    // 0..1
  const int wn = wid & 3;                     // 0..3

  // staging source pointers (inverse-swizzled k offset)
  const int kofs = ((tid & 7) * 8) ^ (((tid >> 3) & 7) << 3);
  const int rth = tid >> 3;                   // 0..63
  const unsigned short* aptr[4];
  const unsigned short* bptr[4];
  const unsigned short* wb = w1t + (size_t)e * HDIM * DIN;
#pragma unroll
  for (int i = 0; i < 4; i++) {
    int r = rth + i * 64;
    int ta = ptok[e * NTOK + min(m0 + r, ce - 1)];
    aptr[i] = xbf + (size_t)ta * DIN + kofs;
    bptr[i] = wb + (size_t)(n0 + r) * DIN + kofs;
  }

  const int fr = lane & 15;
  const int hi = lane >> 4;
  const unsigned cxor = (unsigned)((fr & 7) << 4);
  const unsigned ldsbase = (unsigned)(size_t)(void*)lds;
  const unsigned aoff = ldsbase + (unsigned)((wm * 128 + fr) * 128);
  const unsigned boff = ldsbase + 32768u + (unsigned)((wn * 64 + fr) * 128);
  const unsigned kx0 = (unsigned)((hi * 16) ^ cxor);
  const unsigned kx1 = (unsigned)((64 + hi * 16) ^ cxor);

  f32x4 acc[8][4] = {};
  bf16x8 areg[4][2], b0reg[2][2], b1reg[2][2];

  KLOOP(DIN / 64);

  // epilogue: bias + relu + bf16 store
#pragma unroll
  for (int am = 0; am < 8; am++) {
    int rbase = wm * 128 + am * 16 + hi * 4;
#pragma unroll
    for (int r = 0; r < 4; r++) {
      int grow = m0 + rbase + r;
      if (grow >= ce) continue;
      size_t hoff = (size_t)(oe + grow) * HDIM;
#pragma unroll
      for (int an = 0; an < 4; an++) {
        int col = n0 + wn * 64 + an * 16 + fr;
        float v = acc[am][an][r] + b1[e * HDIM + col];
        h[hoff + col] = f2bf(v > 0.f ? v : 0.f);
      }
    }
  }
}

// ---------------- grouped GEMM2: out += w * (h @ W2[e] + b2[e]) ------------
__global__ __launch_bounds__(512, 1) void gemm2_kernel(
    const unsigned short* __restrict__ h,     // [NPAIR][HDIM]
    const unsigned short* __restrict__ w2t,   // [E][DOUT][HDIM]
    const float* __restrict__ b2,             // [E][DOUT]
    const int* __restrict__ cnt, const int* __restrict__ off,
    const int* __restrict__ ptok, const float* __restrict__ pw,
    float* __restrict__ out)                  // [NTOK][DOUT]
{
  extern __shared__ char lds[];
  const int bid = blockIdx.x;
  const int e = bid & 7;
  const int ce = cnt[e];
  const int idx = bid >> 3;
  const int mt = idx >> 2;                    // NT = DOUT/256 = 4
  const int nt = idx & 3;
  const int m0 = mt * 256;
  if (m0 >= ce) return;
  const int n0 = nt * 256;
  const int oe = off[e];
  const int tid = threadIdx.x;
  const int lane = tid & 63;
  const int wid = tid >> 6;
  const int wm = wid >> 2;
  const int wn = wid & 3;

  const int kofs = ((tid & 7) * 8) ^ (((tid >> 3) & 7) << 3);
  const int rth = tid >> 3;
  const unsigned short* aptr[4];
  const unsigned short* bptr[4];
  const unsigned short* wb = w2t + (size_t)e * DOUT * HDIM;
#pragma unroll
  for (int i = 0; i < 4; i++) {
    int r = rth + i * 64;
    int rc = min(m0 + r, ce - 1);
    aptr[i] = h + (size_t)(oe + rc) * HDIM + kofs;
    bptr[i] = wb + (size_t)(n0 + r) * HDIM + kofs;
  }

  const int fr = lane & 15;
  const int hi = lane >> 4;
  const unsigned cxor = (unsigned)((fr & 7) << 4);
  const unsigned ldsbase = (unsigned)(size_t)(void*)lds;
  const unsigned aoff = ldsbase + (unsigned)((wm * 128 + fr) * 128);
  const unsigned boff = ldsbase + 32768u + (unsigned)((wn * 64 + fr) * 128);
  const unsigned kx0 = (unsigned)((hi * 16) ^ cxor);
  const unsigned kx1 = (unsigned)((64 + hi * 16) ^ cxor);

  f32x4 acc[8][4] = {};
  bf16x8 areg[4][2], b0reg[2][2], b1reg[2][2];

  KLOOP(HDIM / 64);

  // epilogue: weighted atomic accumulate
#pragma unroll
  for (int am = 0; am < 8; am++) {
    int rbase = wm * 128 + am * 16 + hi * 4;
#pragma unroll
    for (int r = 0; r < 4; r++) {
      int grow = m0 + rbase + r;
      if (grow >= ce) continue;
      int pidx = e * NTOK + grow;
      int token = ptok[pidx];
      float w = pw[pidx];
#pragma unroll
      for (int an = 0; an < 4; an++) {
        int col = n0 + wn * 64 + an * 16 + fr;
        float v = (acc[am][an][r] + b2[e * DOUT + col]) * w;
        atomicAdd(out + (size_t)token * DOUT + col, v);
      }
    }
  }
}

extern "C" void kernel_launch(void* const* d_in, const int* in_sizes, int n_in,
                              void* d_out, int out_size, void* d_ws, size_t ws_size,
                              hipStream_t stream) {
  const float* x  = (const float*)d_in[0];
  const float* Wg = (const float*)d_in[1];
  const float* W1 = (const float*)d_in[2];
  const float* b1 = (const float*)d_in[3];
  const float* W2 = (const float*)d_in[4];
  const float* b2 = (const float*)d_in[5];
  float* out = (float*)d_out;

  char* ws = (char*)d_ws;
  size_t o = 0;
  auto nxt = [&](size_t b) { char* p = ws + o; o = (o + b + 255) & ~(size_t)255; return p; };
  int* cnt = (int*)nxt(64);
  int* off = (int*)nxt(64);
  int* ptok = (int*)nxt((size_t)NEXP * NTOK * 4);
  float* pw = (float*)nxt((size_t)NEXP * NTOK * 4);
  unsigned short* xbf = (unsigned short*)nxt((size_t)NTOK * DIN * 2);
  unsigned short* w1t = (unsigned short*)nxt((size_t)NEXP * HDIM * DIN * 2);
  unsigned short* w2t = (unsigned short*)nxt((size_t)NEXP * DOUT * HDIM * 2);
  unsigned short* hbuf = (unsigned short*)nxt((size_t)NPAIR * HDIM * 2);

  hipFuncSetAttribute((const void*)gemm1_kernel,
                      hipFuncAttributeMaxDynamicSharedMemorySize, 131072);
  hipFuncSetAttribute((const void*)gemm2_kernel,
                      hipFuncAttributeMaxDynamicSharedMemorySize, 131072);

  hipMemsetAsync(cnt, 0, 64, stream);
  hipMemsetAsync(out, 0, (size_t)NTOK * DOUT * 4, stream);

  gate_kernel<<<NTOK / 4, 256, 0, stream>>>(x, Wg, cnt, ptok, pw);
  scan_kernel<<<1, 64, 0, stream>>>(cnt, off);
  cvt_bf16_kernel<<<(NTOK * DIN / 8) / 256, 256, 0, stream>>>(x, xbf, NTOK * DIN);
  transpose_cvt<<<dim3(HDIM / 64, DIN / 64, NEXP), 256, 0, stream>>>(W1, w1t, DIN, HDIM);
  transpose_cvt<<<dim3(DOUT / 64, HDIM / 64, NEXP), 256, 0, stream>>>(W2, w2t, HDIM, DOUT);

  gemm1_kernel<<<8 * (NTOK / 256) * (HDIM / 256), 512, 131072, stream>>>(
      xbf, w1t, b1, cnt, off, ptok, hbuf);
  gemm2_kernel<<<8 * (NTOK / 256) * (DOUT / 256), 512, 131072, stream>>>(
      hbuf, w2t, b2, cnt, off, ptok, pw, out);
}